// Round 10
// baseline (197.657 us; speedup 1.0000x reference)
//
#include <hip/hip_runtime.h>
#include <hip/hip_bf16.h>
#include <stdint.h>

typedef __attribute__((ext_vector_type(4)))  float f32x4;
typedef __attribute__((ext_vector_type(16))) float f32x16;
typedef __attribute__((ext_vector_type(8)))  short bf16x8;
typedef __attribute__((ext_vector_type(8)))  ushort u16x8;

constexpr int IN_DIM  = 128;
constexpr int OUT_DIM = 128;
constexpr int BLOCK   = 256;              // 4 waves; wave w owns out cols w*32..+32
constexpr int TILE_ROWS = 32;             // one tile = 32 rows
constexpr int TILES_PER_BLOCK = 8;        // 256 rows per block
constexpr int ROWS_PER_BLOCK = TILE_ROWS * TILES_PER_BLOCK;

// v[o][k] = sign(round(sign)) * 2^round(clamp(shift,-14,0))  (exact in bf16)
__device__ __forceinline__ bf16x8 build_seg(const float* __restrict__ shiftp,
                                            const float* __restrict__ signp,
                                            int row, int j)
{
    const int g = row * IN_DIM + j * 8;
    f32x4 sh0 = *reinterpret_cast<const f32x4*>(shiftp + g);
    f32x4 sh1 = *reinterpret_cast<const f32x4*>(shiftp + g + 4);
    f32x4 sg0 = *reinterpret_cast<const f32x4*>(signp + g);
    f32x4 sg1 = *reinterpret_cast<const f32x4*>(signp + g + 4);
    union { ushort u[8]; bf16x8 v; } tmp;
    #pragma unroll
    for (int e = 0; e < 8; ++e) {
        float sh = (e < 4) ? sh0[e] : sh1[e - 4];
        float sg = (e < 4) ? sg0[e] : sg1[e - 4];
        sh = fminf(fmaxf(sh, -14.0f), 0.0f);
        const int   si = (int)rintf(sh);      // round-half-even like jnp.round
        const float rs = rintf(sg);           // {-1, 0, 1}
        ushort bits = 0;
        if (rs != 0.0f)
            bits = (ushort)(((rs < 0.0f) ? 0x8000u : 0u) |
                            (unsigned)((127 + si) << 7));  // exact 2^si in bf16
        tmp.u[e] = bits;
    }
    return tmp.v;
}

// bf16 LDS tile: 32 rows x 128 bf16 (256 B/row), 16B-chunk XOR swizzle
// chunk c of row r stored at c ^ (r & 7)  -> fragment reads spread 8 rows
// across all 32 banks instead of a 32-way same-bank pileup.
//
// Staging (per thread, tile = 8 KB bf16 from 16 KB f32):
//   q in {t, t+256}: global floats q*8 .. q*8+8  ->  bf16 chunk (row q>>4, c q&15)
// Global loads are consecutive 16B per lane = fully coalesced dwordx4.
__global__ __launch_bounds__(BLOCK, 4)
void linshift_main(const float* __restrict__ x,
                   const float* __restrict__ shiftp,
                   const float* __restrict__ signp,
                   const float* __restrict__ biasp,
                   float* __restrict__ out)
{
    __shared__ ushort buf[2][TILE_ROWS * IN_DIM];   // 2 x 8 KB bf16 tiles

    const int t    = threadIdx.x;
    const int ct   = t >> 6;        // wave id = output column block
    const int lane = t & 63;
    const int ml   = lane & 31;     // A-row / D-col within 32
    const int hi   = lane >> 5;
    const int o    = ct * 32 + ml;  // this thread's output column

    // loop-invariant B fragments (L2/L3-hot inputs)
    bf16x8 vb[8];
    #pragma unroll
    for (int ks = 0; ks < 8; ++ks)
        vb[ks] = build_seg(shiftp, signp, o, ks * 2 + hi);
    const float bv = floorf(biasp[o] * 65536.0f) * (1.0f / 65536.0f);  // round_to_fixed

    const long long brow0 = (long long)blockIdx.x * ROWS_PER_BLOCK;
    const float* xblock = x + brow0 * IN_DIM;

    f32x4 gA[4], gB[4];

    // issue 4 coalesced loads of one 16KB f32 tile into regs
    auto load_tile = [&](int tl, f32x4 g[4]) {
        const float* p = xblock + (long long)tl * TILE_ROWS * IN_DIM;
        g[0] = *reinterpret_cast<const f32x4*>(p + t * 8);
        g[1] = *reinterpret_cast<const f32x4*>(p + t * 8 + 4);
        g[2] = *reinterpret_cast<const f32x4*>(p + (t + 256) * 8);
        g[3] = *reinterpret_cast<const f32x4*>(p + (t + 256) * 8 + 4);
    };
    // convert 16 f32 -> 16 bf16, 2x ds_write_b128 (swizzled)
    auto write_tile = [&](int bi, f32x4 g[4]) {
        #pragma unroll
        for (int i = 0; i < 2; ++i) {
            const int q   = t + i * 256;
            const int row = q >> 4;
            const int c   = q & 15;
            const int sc  = c ^ (row & 7);
            union { ushort u[8]; u16x8 v; } tmp;
            #pragma unroll
            for (int e = 0; e < 4; ++e) {
                __hip_bfloat16 h0 = __float2bfloat16(g[2 * i][e]);
                __hip_bfloat16 h1 = __float2bfloat16(g[2 * i + 1][e]);
                tmp.u[e]     = *reinterpret_cast<const ushort*>(&h0);
                tmp.u[e + 4] = *reinterpret_cast<const ushort*>(&h1);
            }
            *reinterpret_cast<u16x8*>(&buf[bi][row * IN_DIM + sc * 8]) = tmp.v;
        }
    };

    // prologue: tile0 -> buf0; tile1 loads in flight in gA
    load_tile(0, gA);
    write_tile(0, gA);
    load_tile(1, gA);
    __syncthreads();                       // buf0 fully written

    #pragma unroll
    for (int tl = 0; tl < TILES_PER_BLOCK; ++tl) {
        // phase 1: issue prefetch loads for tile tl+2
        if (tl + 2 < TILES_PER_BLOCK) load_tile(tl + 2, gB);
        __builtin_amdgcn_sched_barrier(0);

        // phase 2: compute tile tl from buf[tl&1]
        const ushort* bp = buf[tl & 1];
        bf16x8 a[8];
        #pragma unroll
        for (int ks = 0; ks < 8; ++ks)
            a[ks] = *reinterpret_cast<const bf16x8*>(
                &bp[ml * IN_DIM + (((ks * 2 + hi) ^ (ml & 7)) * 8)]);

        f32x16 acc;
        #pragma unroll
        for (int r = 0; r < 16; ++r) acc[r] = bv;    // bias folded into acc init
        #pragma unroll
        for (int ks = 0; ks < 8; ++ks)
            acc = __builtin_amdgcn_mfma_f32_32x32x16_bf16(a[ks], vb[ks], acc, 0, 0, 0);

        // D: col o, row m = (r&3) + 8*(r>>2) + 4*hi -> full-128B-line nt stores
        float* op = out + (brow0 + (long long)tl * TILE_ROWS) * OUT_DIM + o;
        #pragma unroll
        for (int r = 0; r < 16; ++r) {
            const int m = (r & 3) + 8 * (r >> 2) + 4 * hi;
            __builtin_nontemporal_store(acc[r], op + m * OUT_DIM);
        }
        __builtin_amdgcn_sched_barrier(0);

        // phase 3: convert tile tl+1 (loads issued last iter) -> other buffer
        if (tl + 1 < TILES_PER_BLOCK) write_tile((tl + 1) & 1, gA);
        __syncthreads();   // writes of tl+1 visible; all reads of tl done

        #pragma unroll
        for (int i = 0; i < 4; ++i) gA[i] = gB[i];
    }
}

extern "C" void kernel_launch(void* const* d_in, const int* in_sizes, int n_in,
                              void* d_out, int out_size, void* d_ws, size_t ws_size,
                              hipStream_t stream) {
    const float* x  = (const float*)d_in[0];
    const float* sh = (const float*)d_in[1];
    const float* sg = (const float*)d_in[2];
    const float* b  = (const float*)d_in[3];
    float* out = (float*)d_out;

    const int N = in_sizes[0] / IN_DIM;            // 524288
    const int grid = N / ROWS_PER_BLOCK;           // 2048 (exact)
    linshift_main<<<grid, BLOCK, 0, stream>>>(x, sh, sg, b, out);
}